// Round 7
// baseline (1502.664 us; speedup 1.0000x reference)
//
#include <hip/hip_runtime.h>

#define NPTS 100000
#define CC   64
#define KK   27
#define TOT  (KK * NPTS)        // 2,700,000 edges
#define SEGS (NPTS * KK)        // 2,700,000 (k,dst) segments, k-major
#define EPSBN 1e-5f
#define MT   128                // output rows per conv block
#define APAD 72                 // padded LDS row stride in bf16 elems (144B)
#define KH0  14                 // k-split: half0 = [0,14), half1 = [14,27)

#define NRANGE 32               // dst ranges per slice
#define RSIZE  (NPTS / NRANGE)  // 3125 dsts per range
#define CAP    4608             // LDS edge-list capacity
#define CHUNK  12500            // edges per k_rhist block (divides NPTS)

typedef float          f32x4  __attribute__((ext_vector_type(4)));
typedef short          bf16x8 __attribute__((ext_vector_type(8)));
typedef unsigned int   u32x4  __attribute__((ext_vector_type(4)));
typedef unsigned short u16x4  __attribute__((ext_vector_type(4)));
typedef int            i32x4  __attribute__((ext_vector_type(4)));

__device__ __forceinline__ float bf2f(unsigned short h) {
    return __uint_as_float(((unsigned int)h) << 16);
}
__device__ __forceinline__ unsigned short f2bf(float f) {
    unsigned int u = __float_as_uint(f);
    u = (u + 0x7fffu + ((u >> 16) & 1u)) >> 16;
    return (unsigned short)u;
}

// barrier that drains LDS only (lgkmcnt(0)) — keeps global prefetches in flight.
__device__ __forceinline__ void lds_barrier() {
    asm volatile("" ::: "memory");
    __builtin_amdgcn_s_waitcnt(0xC07F);
    __builtin_amdgcn_s_barrier();
    asm volatile("" ::: "memory");
}

// ---------------- prep: x -> bf16 ----------------
__global__ void k_convert_x(const float* __restrict__ x, unsigned short* __restrict__ xb) {
    int id = blockIdx.x * 256 + threadIdx.x;
    f32x4 v = ((const f32x4*)x)[id];
    u16x4 o;
#pragma unroll
    for (int j = 0; j < 4; ++j) o[j] = f2bf(v[j]);
    ((u16x4*)xb)[id] = o;
}

// ---------------- prep: W[k][cin][cout] fp32 -> Wt[k][cout][cin] bf16 ----------------
__global__ void k_prep_w(const float* __restrict__ W1, const float* __restrict__ W2,
                         unsigned short* __restrict__ Wt1, unsigned short* __restrict__ Wt2) {
    int id = blockIdx.x * 256 + threadIdx.x;
    int which = id / (KK * CC * CC);
    int r = id % (KK * CC * CC);
    int k = r / (CC * CC);
    int rem = r % (CC * CC);
    int cin = rem / CC, cout = rem % CC;
    const float* W = which ? W2 : W1;
    unsigned short* Wt = which ? Wt2 : Wt1;
    Wt[k * CC * CC + cout * CC + cin] = f2bf(W[r]);
}

// ---------------- CSR build: per-(k,range) counting sort ----------------
__global__ void k_rhist(const int* __restrict__ out_idx, int* __restrict__ rcnt) {
    __shared__ int rc[NRANGE];
    int t = threadIdx.x;
    if (t < NRANGE) rc[t] = 0;
    __syncthreads();
    int j0 = blockIdx.x * CHUNK;
    int k = j0 / NPTS;
    const i32x4* src = (const i32x4*)(out_idx + j0);
    for (int ii = t; ii < CHUNK / 4; ii += 256) {
        i32x4 d = src[ii];
#pragma unroll
        for (int q = 0; q < 4; ++q) atomicAdd(&rc[d[q] / RSIZE], 1);
    }
    __syncthreads();
    if (t < NRANGE) atomicAdd(&rcnt[k * NRANGE + t], rc[t]);
}

__global__ void k_rscan(const int* __restrict__ rcnt, int* __restrict__ rbase,
                        int* __restrict__ offs) {
    int t = threadIdx.x;
    if (t < KK) {
        int run = t * NPTS;
        for (int r = 0; r < NRANGE; ++r) {
            rbase[t * NRANGE + r] = run;
            run += rcnt[t * NRANGE + r];
        }
    }
    if (t == 0) offs[SEGS] = TOT;
}

__global__ __launch_bounds__(256) void k_sort(
    const int* __restrict__ out_idx, const int* __restrict__ in_idx,
    const int* __restrict__ rbase,
    int* __restrict__ offs, int* __restrict__ entries) {
    __shared__ int cnt[RSIZE];
    __shared__ unsigned list[CAP];
    __shared__ int psum[256];
    __shared__ int nlist;

    const int t = threadIdx.x;
    const int k = blockIdx.x / NRANGE;
    const int r = blockIdx.x % NRANGE;
    const int dlo = r * RSIZE;

    for (int i = t; i < RSIZE; i += 256) cnt[i] = 0;
    if (t == 0) nlist = 0;
    __syncthreads();

    const i32x4* dsrc = (const i32x4*)(out_idx + k * NPTS);
    const i32x4* ssrc = (const i32x4*)(in_idx + k * NPTS);
    for (int ii = t; ii < NPTS / 4; ii += 256) {
        i32x4 d4 = dsrc[ii];
        i32x4 s4 = ssrc[ii];
#pragma unroll
        for (int q = 0; q < 4; ++q) {
            unsigned dloc = (unsigned)(d4[q] - dlo);
            if (dloc < RSIZE) {
                atomicAdd(&cnt[dloc], 1);
                int p = atomicAdd(&nlist, 1);
                if (p < CAP) list[p] = (dloc << 17) | (unsigned)s4[q];
            }
        }
    }
    __syncthreads();

    const int T = (RSIZE + 255) / 256;    // 13
    int vals[T];
    int s = 0;
#pragma unroll
    for (int q = 0; q < T; ++q) {
        int i = t * T + q;
        int v = (i < RSIZE) ? cnt[i] : 0;
        vals[q] = v;
        s += v;
    }
    psum[t] = s;
    __syncthreads();
    for (int o = 1; o < 256; o <<= 1) {
        int pv = (t >= o) ? psum[t - o] : 0;
        __syncthreads();
        psum[t] += pv;
        __syncthreads();
    }
    int run = rbase[blockIdx.x] + (t ? psum[t - 1] : 0);
#pragma unroll
    for (int q = 0; q < T; ++q) {
        int i = t * T + q;
        if (i < RSIZE) {
            offs[k * NPTS + dlo + i] = run;
            cnt[i] = run;
            run += vals[q];
        }
    }
    __syncthreads();

    int nl = nlist < CAP ? nlist : CAP;
    for (int i = t; i < nl; i += 256) {
        unsigned u = list[i];
        int dloc = u >> 17;
        int src = u & 0x1FFFF;
        int p = atomicAdd(&cnt[dloc], 1);
        entries[p] = src;
    }
}

// ---------------- conv v5: R3 pipeline, k-range split across 2 blocks ----------------
// half 0: k in [0,KH0) -> y1 (bf16 partial); half 1: k in [KH0,KK) -> y2.
__global__ __launch_bounds__(256, 5) void k_conv(
    const unsigned short* __restrict__ xb,    // [N][64] bf16
    const unsigned short* __restrict__ Wt,    // [27][cout=64][cin=64] bf16
    const int* __restrict__ offs,             // [SEGS+1], k-major
    const int* __restrict__ entries,          // [TOT] src indices
    unsigned short* __restrict__ y1,          // [N][64] bf16 partial (k-half 0)
    unsigned short* __restrict__ y2)          // [N][64] bf16 partial (k-half 1)
{
    __shared__ __align__(16) unsigned short Bsh[2][CC * APAD];  // 18432 B
    __shared__ unsigned seginfo[KH0 * MT];                      // 7168 B: (gstart<<6)|cnt
    __shared__ int esh[2][MT];                                  // 1024 B: entry ring
    __shared__ int maxcnt[KH0];

    const int tid  = threadIdx.x;
    const int lane = tid & 63;
    const int wave = tid >> 6;
    const int quad = lane >> 4;
    const int l16  = lane & 15;
    const int half = blockIdx.x & 1;
    const int i0   = (blockIdx.x >> 1) * MT;
    const int klo  = half ? KH0 : 0;
    const int knum = half ? (KK - KH0) : KH0;
    const unsigned short* Wb = Wt + klo * CC * CC;
    unsigned short* yout = half ? y2 : y1;

    // ---- prologue: seginfo + per-k max count (local k) ----
    if (tid < KH0) maxcnt[tid] = 1;
    __syncthreads();
    for (int idx = tid; idx < knum * MT; idx += 256) {
        int k = idx >> 7;
        int r = idx & (MT - 1);
        int gi = i0 + r;
        unsigned pack = 0;
        int c = 0;
        if (gi < NPTS) {
            int seg = (klo + k) * NPTS + gi;
            int b = offs[seg];
            c = offs[seg + 1] - b;
            c = c > 63 ? 63 : c;
            pack = ((unsigned)b << 6) | (unsigned)c;
        }
        seginfo[idx] = pack;
        atomicMax(&maxcnt[k], c);
    }
    // ---- B warm-up: Bsh[0] = Wb[0], prefetch Wb[1] ----
    const int bofs = tid * 16;
    const int brow = bofs >> 6, bcol = bofs & 63;
    u32x4 bw0 = ((const u32x4*)Wb)[tid * 2];
    u32x4 bw1 = ((const u32x4*)Wb)[tid * 2 + 1];
    *(u32x4*)&Bsh[0][brow * APAD + bcol]     = bw0;
    *(u32x4*)&Bsh[0][brow * APAD + bcol + 8] = bw1;
    bw0 = ((const u32x4*)(Wb + CC * CC))[tid * 2];
    bw1 = ((const u32x4*)(Wb + CC * CC))[tid * 2 + 1];
    __syncthreads();          // seginfo + maxcnt + Bsh[0] visible

    // ---- cursors (local k) ----
    int T = 0;
    for (int k = 0; k < knum; ++k) T += maxcnt[k];
    int ka = 0, ja = 0;                 // iter t
    int kb = 0, jb = 0;                 // iter t+1
    int kc = 0, jc = 0;                 // iter t+2
    {
        jb++; if (jb >= maxcnt[kb]) { jb = 0; if (kb < knum - 1) kb++; }
        kc = kb; jc = jb;
        jc++; if (jc >= maxcnt[kc]) { jc = 0; if (kc < knum - 1) kc++; }
    }

    // ---- esh warm-up: entries for iter0 -> esh[0], iter1 -> esh[1] ----
    if (tid < MT) {
        unsigned s0 = seginfo[ka * MT + tid];
        unsigned s1 = seginfo[kb * MT + tid];
        int a0 = min((int)(s0 >> 6) + ja, TOT - 1);
        int a1 = min((int)(s1 >> 6) + jb, TOT - 1);
        esh[0][tid] = entries[a0];
        esh[1][tid] = entries[a1];
    }
    __syncthreads();

    // ---- cfrag warm-up for iter 0 ----
    const int row0 = wave * 32 + l16;       // mt = 0
    const int row1 = row0 + 16;             // mt = 1
    const bf16x8 z = {0, 0, 0, 0, 0, 0, 0, 0};
    bf16x8 cfr[2][2];
    {
        cfr[0][0] = z; cfr[0][1] = z; cfr[1][0] = z; cfr[1][1] = z;
        int e0 = esh[0][row0], e1 = esh[0][row1];
        unsigned sA = seginfo[ka * MT + row0];
        unsigned sB = seginfo[ka * MT + row1];
        if (ja < (int)(sA & 63)) {
            const unsigned short* p = xb + (long)e0 * CC + quad * 8;
            cfr[0][0] = *(const bf16x8*)p;
            cfr[0][1] = *(const bf16x8*)(p + 32);
        }
        if (ja < (int)(sB & 63)) {
            const unsigned short* p = xb + (long)e1 * CC + quad * 8;
            cfr[1][0] = *(const bf16x8*)p;
            cfr[1][1] = *(const bf16x8*)(p + 32);
        }
    }
    lds_barrier();   // protect esh[0] reads above from t=0's esh[0] rewrite

    f32x4 acc[2][4];
#pragma unroll
    for (int mt = 0; mt < 2; ++mt)
#pragma unroll
        for (int nt = 0; nt < 4; ++nt) acc[mt][nt] = (f32x4){0.f, 0.f, 0.f, 0.f};

    bf16x8 bfr[4][2];

    for (int t = 0; t < T; ++t) {
        // step1: issue entries load for iter t+2 (loader role)
        int er = 0;
        if (tid < MT) {
            unsigned sc = seginfo[kc * MT + tid];
            int ac = min((int)(sc >> 6) + jc, TOT - 1);
            er = entries[ac];
        }
        // step2: issue frag loads for iter t+1 from esh[(t+1)&1]
        bf16x8 nfr[2][2];
        {
            nfr[0][0] = z; nfr[0][1] = z; nfr[1][0] = z; nfr[1][1] = z;
            int slot = (t + 1) & 1;
            int ne0 = esh[slot][row0], ne1 = esh[slot][row1];
            unsigned sb0 = seginfo[kb * MT + row0];
            unsigned sb1 = seginfo[kb * MT + row1];
            if (jb < (int)(sb0 & 63)) {
                const unsigned short* p = xb + (long)ne0 * CC + quad * 8;
                nfr[0][0] = *(const bf16x8*)p;
                nfr[0][1] = *(const bf16x8*)(p + 32);
            }
            if (jb < (int)(sb1 & 63)) {
                const unsigned short* p = xb + (long)ne1 * CC + quad * 8;
                nfr[1][0] = *(const bf16x8*)p;
                nfr[1][1] = *(const bf16x8*)(p + 32);
            }
        }
        // step3: B management (block-uniform branch, once per k)
        if (ja == 0) {
#pragma unroll
            for (int nt = 0; nt < 4; ++nt)
#pragma unroll
                for (int kt = 0; kt < 2; ++kt)
                    bfr[nt][kt] = *(const bf16x8*)&Bsh[ka & 1][(nt * 16 + l16) * APAD +
                                                              kt * 32 + quad * 8];
            *(u32x4*)&Bsh[(ka + 1) & 1][brow * APAD + bcol]     = bw0;
            *(u32x4*)&Bsh[(ka + 1) & 1][brow * APAD + bcol + 8] = bw1;
            int kn = ka + 2 < knum ? ka + 2 : knum - 1;
            bw0 = ((const u32x4*)(Wb + kn * CC * CC))[tid * 2];
            bw1 = ((const u32x4*)(Wb + kn * CC * CC))[tid * 2 + 1];
        }
        // step4: MFMA for iter t (16 MFMAs)
#pragma unroll
        for (int mt = 0; mt < 2; ++mt)
#pragma unroll
            for (int nt = 0; nt < 4; ++nt) {
                acc[mt][nt] = __builtin_amdgcn_mfma_f32_16x16x32_bf16(
                    cfr[mt][0], bfr[nt][0], acc[mt][nt], 0, 0, 0);
                acc[mt][nt] = __builtin_amdgcn_mfma_f32_16x16x32_bf16(
                    cfr[mt][1], bfr[nt][1], acc[mt][nt], 0, 0, 0);
            }
        // step5: loader commits entry for iter t+2 into slot (t+2)&1 == t&1
        if (tid < MT) esh[t & 1][tid] = er;
        // step6: rotate + advance
        cfr[0][0] = nfr[0][0]; cfr[0][1] = nfr[0][1];
        cfr[1][0] = nfr[1][0]; cfr[1][1] = nfr[1][1];
        ka = kb; ja = jb;
        kb = kc; jb = jc;
        jc++; if (jc >= maxcnt[kc]) { jc = 0; if (kc < knum - 1) kc++; }
        lds_barrier();
    }

    // epilogue: D row = quad*4 + rr, col = l16; store bf16 partial
#pragma unroll
    for (int mt = 0; mt < 2; ++mt) {
        int rbase_ = i0 + wave * 32 + mt * 16 + quad * 4;
#pragma unroll
        for (int nt = 0; nt < 4; ++nt) {
            int col = nt * 16 + l16;
#pragma unroll
            for (int rr = 0; rr < 4; ++rr) {
                int gr = rbase_ + rr;
                if (gr < NPTS) yout[(long)gr * CC + col] = f2bf(acc[mt][nt][rr]);
            }
        }
    }
}

// ---------------- BN (y = y1 + y2, bf16 partials) ----------------
__global__ void k_bn_stats(const unsigned short* __restrict__ y1,
                           const unsigned short* __restrict__ y2,
                           float* __restrict__ sums) {
    __shared__ float s1[256], s2[256];
    int t = threadIdx.x;
    int c = t & 63, g = t >> 6;
    float a = 0.f, b = 0.f;
    for (int i = blockIdx.x * 4 + g; i < NPTS; i += gridDim.x * 4) {
        float v = bf2f(y1[(long)i * CC + c]) + bf2f(y2[(long)i * CC + c]);
        a += v; b += v * v;
    }
    s1[t] = a; s2[t] = b;
    __syncthreads();
    if (t < 64) {
        a = s1[t] + s1[t + 64] + s1[t + 128] + s1[t + 192];
        b = s2[t] + s2[t + 64] + s2[t + 128] + s2[t + 192];
        atomicAdd(&sums[t], a);
        atomicAdd(&sums[t + 64], b);
    }
}

__global__ void k_bn_fin(const float* __restrict__ sums, const float* __restrict__ gamma,
                         const float* __restrict__ beta, float* __restrict__ sb) {
    int c = threadIdx.x;   // 64 threads
    float mu  = sums[c] * (1.0f / NPTS);
    float var = sums[c + 64] * (1.0f / NPTS) - mu * mu;
    float s = gamma[c] * rsqrtf(var + EPSBN);
    sb[c] = s;
    sb[c + 64] = beta[c] - mu * s;
}

// a1 = bf16(relu((y1+y2)*s + b))
__global__ void k_apply(const unsigned short* __restrict__ y1,
                        const unsigned short* __restrict__ y2,
                        const float* __restrict__ sb,
                        unsigned short* __restrict__ ab) {
    int id = blockIdx.x * 256 + threadIdx.x;
    u16x4 a4 = ((const u16x4*)y1)[id];
    u16x4 b4 = ((const u16x4*)y2)[id];
    int c0 = (id * 4) & 63;
    u16x4 o;
#pragma unroll
    for (int j = 0; j < 4; ++j) {
        float v = bf2f(a4[j]) + bf2f(b4[j]);
        float t = fmaxf(v * sb[c0 + j] + sb[64 + c0 + j], 0.f);
        o[j] = f2bf(t);
    }
    ((u16x4*)ab)[id] = o;
}

// out = relu((y1+y2)*s + b + x)
__global__ void k_final(const unsigned short* __restrict__ y1,
                        const unsigned short* __restrict__ y2,
                        const float* __restrict__ x,
                        const float* __restrict__ sb, float* __restrict__ out) {
    int id = blockIdx.x * 256 + threadIdx.x;
    u16x4 a4 = ((const u16x4*)y1)[id];
    u16x4 b4 = ((const u16x4*)y2)[id];
    f32x4 xv = ((const f32x4*)x)[id];
    int c0 = (id * 4) & 63;
    f32x4 o;
#pragma unroll
    for (int j = 0; j < 4; ++j) {
        float v = bf2f(a4[j]) + bf2f(b4[j]);
        o[j] = fmaxf(v * sb[c0 + j] + sb[64 + c0 + j] + xv[j], 0.f);
    }
    ((f32x4*)out)[id] = o;
}

extern "C" void kernel_launch(void* const* d_in, const int* in_sizes, int n_in,
                              void* d_out, int out_size, void* d_ws, size_t ws_size,
                              hipStream_t stream) {
    const float* x      = (const float*)d_in[0];
    // d_in[1] = norm_points (unused by the reference math)
    const float* W1     = (const float*)d_in[2];
    const float* gamma1 = (const float*)d_in[3];
    const float* beta1  = (const float*)d_in[4];
    const float* W2     = (const float*)d_in[5];
    const float* gamma2 = (const float*)d_in[6];
    const float* beta2  = (const float*)d_in[7];
    const int* in_idx   = (const int*)d_in[8];
    const int* out_idx  = (const int*)d_in[9];
    float* out = (float*)d_out;

    char* w = (char*)d_ws;
    size_t off = 0;
    auto alloc = [&](size_t bytes) -> char* {
        off = (off + 255) & ~(size_t)255;
        char* p = w + off;
        off += bytes;
        return p;
    };
    int*   rcnt    = (int*)  alloc((size_t)KK * NRANGE * 4);
    float* sums    = (float*)alloc(256 * 4);            // [0:128) layer1, [128:256) layer2
    int*   rbase   = (int*)  alloc((size_t)KK * NRANGE * 4);
    float* sb      = (float*)alloc(256 * 4);
    int*   offs    = (int*)  alloc(((size_t)SEGS + 1) * 4);
    int*   entries = (int*)  alloc((size_t)SEGS * 4);
    unsigned short* xbf = (unsigned short*)alloc((size_t)NPTS * CC * 2);
    unsigned short* Wt1 = (unsigned short*)alloc((size_t)KK * CC * CC * 2);
    unsigned short* Wt2 = (unsigned short*)alloc((size_t)KK * CC * CC * 2);
    unsigned short* y1  = (unsigned short*)alloc((size_t)NPTS * CC * 2);
    unsigned short* y2  = (unsigned short*)alloc((size_t)NPTS * CC * 2);

    // zero rcnt + sums (contiguous; covers alignment gap)
    size_t zlen = (size_t)((char*)(sums + 256) - (char*)rcnt);
    hipMemsetAsync(rcnt, 0, zlen, stream);

    k_convert_x<<<NPTS * CC / 1024, 256, 0, stream>>>(x, xbf);
    k_prep_w<<<(2 * KK * CC * CC) / 256, 256, 0, stream>>>(W1, W2, Wt1, Wt2);
    k_rhist<<<TOT / CHUNK, 256, 0, stream>>>(out_idx, rcnt);
    k_rscan<<<1, 64, 0, stream>>>(rcnt, rbase, offs);
    k_sort<<<KK * NRANGE, 256, 0, stream>>>(out_idx, in_idx, rbase, offs, entries);

    const int CONVB = 2 * ((NPTS + MT - 1) / MT);   // 2 k-halves per row tile
    k_conv<<<CONVB, 256, 0, stream>>>(xbf, Wt1, offs, entries, y1, y2);
    k_bn_stats<<<256, 256, 0, stream>>>(y1, y2, sums);
    k_bn_fin<<<1, 64, 0, stream>>>(sums, gamma1, beta1, sb);
    k_apply<<<NPTS * CC / 1024, 256, 0, stream>>>(y1, y2, sb, xbf);   // a1 overwrites xbf
    k_conv<<<CONVB, 256, 0, stream>>>(xbf, Wt2, offs, entries, y1, y2);
    k_bn_stats<<<256, 256, 0, stream>>>(y1, y2, sums + 128);
    k_bn_fin<<<1, 64, 0, stream>>>(sums + 128, gamma2, beta2, sb + 128);
    k_final<<<NPTS * CC / 1024, 256, 0, stream>>>(y1, y2, x, sb + 128, out);
}

// Round 8
// 672.980 us; speedup vs baseline: 2.2329x; 2.2329x over previous
//
#include <hip/hip_runtime.h>

#define NPTS 100000
#define CC   64
#define KK   27
#define TOT  (KK * NPTS)        // 2,700,000 edges
#define SEGS (NPTS * KK)        // 2,700,000 (k,dst) segments, k-major
#define EPSBN 1e-5f
#define MT   128                // output rows per conv block
#define APAD 72                 // padded LDS row stride in bf16 elems (144B)

#define NRANGE 32               // dst ranges per slice
#define RSIZE  (NPTS / NRANGE)  // 3125 dsts per range
#define CAP    4608             // LDS edge-list capacity
#define CHUNK  12500            // edges per k_rhist block (divides NPTS)

typedef float          f32x4  __attribute__((ext_vector_type(4)));
typedef short          bf16x8 __attribute__((ext_vector_type(8)));
typedef unsigned int   u32x4  __attribute__((ext_vector_type(4)));
typedef unsigned short u16x4  __attribute__((ext_vector_type(4)));
typedef int            i32x4  __attribute__((ext_vector_type(4)));

__device__ __forceinline__ unsigned short f2bf(float f) {
    unsigned int u = __float_as_uint(f);
    u = (u + 0x7fffu + ((u >> 16) & 1u)) >> 16;
    return (unsigned short)u;
}

// barrier that drains LDS only (lgkmcnt(0)) — keeps global prefetches in flight.
__device__ __forceinline__ void lds_barrier() {
    asm volatile("" ::: "memory");
    __builtin_amdgcn_s_waitcnt(0xC07F);
    __builtin_amdgcn_s_barrier();
    asm volatile("" ::: "memory");
}

// ---------------- prep: x -> bf16 ----------------
__global__ void k_convert_x(const float* __restrict__ x, unsigned short* __restrict__ xb) {
    int id = blockIdx.x * 256 + threadIdx.x;
    f32x4 v = ((const f32x4*)x)[id];
    u16x4 o;
#pragma unroll
    for (int j = 0; j < 4; ++j) o[j] = f2bf(v[j]);
    ((u16x4*)xb)[id] = o;
}

// ---------------- prep: W[k][cin][cout] fp32 -> Wt[k][cout][cin] bf16 ----------------
__global__ void k_prep_w(const float* __restrict__ W1, const float* __restrict__ W2,
                         unsigned short* __restrict__ Wt1, unsigned short* __restrict__ Wt2) {
    int id = blockIdx.x * 256 + threadIdx.x;
    int which = id / (KK * CC * CC);
    int r = id % (KK * CC * CC);
    int k = r / (CC * CC);
    int rem = r % (CC * CC);
    int cin = rem / CC, cout = rem % CC;
    const float* W = which ? W2 : W1;
    unsigned short* Wt = which ? Wt2 : Wt1;
    Wt[k * CC * CC + cout * CC + cin] = f2bf(W[r]);
}

// ---------------- CSR build: per-(k,range) counting sort ----------------
__global__ void k_rhist(const int* __restrict__ out_idx, int* __restrict__ rcnt) {
    __shared__ int rc[NRANGE];
    int t = threadIdx.x;
    if (t < NRANGE) rc[t] = 0;
    __syncthreads();
    int j0 = blockIdx.x * CHUNK;
    int k = j0 / NPTS;
    const i32x4* src = (const i32x4*)(out_idx + j0);
    for (int ii = t; ii < CHUNK / 4; ii += 256) {
        i32x4 d = src[ii];
#pragma unroll
        for (int q = 0; q < 4; ++q) atomicAdd(&rc[d[q] / RSIZE], 1);
    }
    __syncthreads();
    if (t < NRANGE) atomicAdd(&rcnt[k * NRANGE + t], rc[t]);
}

__global__ void k_rscan(const int* __restrict__ rcnt, int* __restrict__ rbase,
                        int* __restrict__ offs) {
    int t = threadIdx.x;
    if (t < KK) {
        int run = t * NPTS;
        for (int r = 0; r < NRANGE; ++r) {
            rbase[t * NRANGE + r] = run;
            run += rcnt[t * NRANGE + r];
        }
    }
    if (t == 0) offs[SEGS] = TOT;
}

__global__ __launch_bounds__(256) void k_sort(
    const int* __restrict__ out_idx, const int* __restrict__ in_idx,
    const int* __restrict__ rbase,
    int* __restrict__ offs, int* __restrict__ entries) {
    __shared__ int cnt[RSIZE];
    __shared__ unsigned list[CAP];
    __shared__ int psum[256];
    __shared__ int nlist;

    const int t = threadIdx.x;
    const int k = blockIdx.x / NRANGE;
    const int r = blockIdx.x % NRANGE;
    const int dlo = r * RSIZE;

    for (int i = t; i < RSIZE; i += 256) cnt[i] = 0;
    if (t == 0) nlist = 0;
    __syncthreads();

    const i32x4* dsrc = (const i32x4*)(out_idx + k * NPTS);
    const i32x4* ssrc = (const i32x4*)(in_idx + k * NPTS);
    for (int ii = t; ii < NPTS / 4; ii += 256) {
        i32x4 d4 = dsrc[ii];
        i32x4 s4 = ssrc[ii];
#pragma unroll
        for (int q = 0; q < 4; ++q) {
            unsigned dloc = (unsigned)(d4[q] - dlo);
            if (dloc < RSIZE) {
                atomicAdd(&cnt[dloc], 1);
                int p = atomicAdd(&nlist, 1);
                if (p < CAP) list[p] = (dloc << 17) | (unsigned)s4[q];
            }
        }
    }
    __syncthreads();

    const int T = (RSIZE + 255) / 256;    // 13
    int vals[T];
    int s = 0;
#pragma unroll
    for (int q = 0; q < T; ++q) {
        int i = t * T + q;
        int v = (i < RSIZE) ? cnt[i] : 0;
        vals[q] = v;
        s += v;
    }
    psum[t] = s;
    __syncthreads();
    for (int o = 1; o < 256; o <<= 1) {
        int pv = (t >= o) ? psum[t - o] : 0;
        __syncthreads();
        psum[t] += pv;
        __syncthreads();
    }
    int run = rbase[blockIdx.x] + (t ? psum[t - 1] : 0);
#pragma unroll
    for (int q = 0; q < T; ++q) {
        int i = t * T + q;
        if (i < RSIZE) {
            offs[k * NPTS + dlo + i] = run;
            cnt[i] = run;
            run += vals[q];
        }
    }
    __syncthreads();

    int nl = nlist < CAP ? nlist : CAP;
    for (int i = t; i < nl; i += 256) {
        unsigned u = list[i];
        int dloc = u >> 17;
        int src = u & 0x1FFFF;
        int p = atomicAdd(&cnt[dloc], 1);
        entries[p] = src;
    }
}

// ---------------- conv v6: R3 pipeline with ring-3 (2-round frag-load cover) ---------
__global__ __launch_bounds__(256, 3) void k_conv(
    const unsigned short* __restrict__ xb,    // [N][64] bf16
    const unsigned short* __restrict__ Wt,    // [27][cout=64][cin=64] bf16
    const int* __restrict__ offs,             // [SEGS+1], k-major
    const int* __restrict__ entries,          // [TOT] src indices
    float* __restrict__ y)                    // [N][64] fp32
{
    __shared__ __align__(16) unsigned short Bsh[2][CC * APAD];  // 18432 B
    __shared__ unsigned seginfo[KK * MT];                       // 13824 B: (gstart<<6)|cnt
    __shared__ int esh[3][MT];                                  // 1536 B: entry ring
    __shared__ int maxcnt[KK];

    const int tid  = threadIdx.x;
    const int lane = tid & 63;
    const int wave = tid >> 6;
    const int quad = lane >> 4;
    const int l16  = lane & 15;
    const int i0   = blockIdx.x * MT;

    // ---- prologue: seginfo + per-k max count ----
    if (tid < KK) maxcnt[tid] = 1;
    __syncthreads();
    for (int idx = tid; idx < KK * MT; idx += 256) {
        int k = idx >> 7;
        int r = idx & (MT - 1);
        int gi = i0 + r;
        unsigned pack = 0;
        int c = 0;
        if (gi < NPTS) {
            int seg = k * NPTS + gi;
            int b = offs[seg];
            c = offs[seg + 1] - b;
            c = c > 63 ? 63 : c;
            pack = ((unsigned)b << 6) | (unsigned)c;
        }
        seginfo[idx] = pack;
        atomicMax(&maxcnt[k], c);
    }
    // ---- B warm-up: Bsh[0] = Wt[0], prefetch Wt[1] ----
    const int bofs = tid * 16;
    const int brow = bofs >> 6, bcol = bofs & 63;
    u32x4 bw0 = ((const u32x4*)Wt)[tid * 2];
    u32x4 bw1 = ((const u32x4*)Wt)[tid * 2 + 1];
    *(u32x4*)&Bsh[0][brow * APAD + bcol]     = bw0;
    *(u32x4*)&Bsh[0][brow * APAD + bcol + 8] = bw1;
    bw0 = ((const u32x4*)(Wt + CC * CC))[tid * 2];
    bw1 = ((const u32x4*)(Wt + CC * CC))[tid * 2 + 1];
    __syncthreads();          // seginfo + maxcnt + Bsh[0] visible

    // ---- cursors: a=iter t, b=t+1, c=t+2, d=t+3 ----
    int T = 0;
    for (int k = 0; k < KK; ++k) T += maxcnt[k];
    int ka = 0, ja = 0, kb = 0, jb = 0, kc = 0, jc = 0, kd = 0, jd = 0;
    {
        jb = 1; if (jb >= maxcnt[kb]) { jb = 0; if (kb < KK - 1) kb++; }
        kc = kb; jc = jb;
        jc++; if (jc >= maxcnt[kc]) { jc = 0; if (kc < KK - 1) kc++; }
        kd = kc; jd = jc;
        jd++; if (jd >= maxcnt[kd]) { jd = 0; if (kd < KK - 1) kd++; }
    }

    // ---- esh warm-up: entries for iters 0,1,2 -> slots 0,1,2 ----
    if (tid < MT) {
        unsigned s0 = seginfo[ka * MT + tid];
        unsigned s1 = seginfo[kb * MT + tid];
        unsigned s2 = seginfo[kc * MT + tid];
        esh[0][tid] = entries[min((int)(s0 >> 6) + ja, TOT - 1)];
        esh[1][tid] = entries[min((int)(s1 >> 6) + jb, TOT - 1)];
        esh[2][tid] = entries[min((int)(s2 >> 6) + jc, TOT - 1)];
    }
    __syncthreads();

    // ---- frag warm-up: cfr for iter0 (slot0), f1 for iter1 (slot1) ----
    const int row0 = wave * 32 + l16;       // mt = 0
    const int row1 = row0 + 16;             // mt = 1
    const bf16x8 z = {0, 0, 0, 0, 0, 0, 0, 0};
    bf16x8 cfr[2][2], f1[2][2];
    {
        cfr[0][0] = z; cfr[0][1] = z; cfr[1][0] = z; cfr[1][1] = z;
        int e0 = esh[0][row0], e1 = esh[0][row1];
        unsigned sA = seginfo[ka * MT + row0];
        unsigned sB = seginfo[ka * MT + row1];
        if (ja < (int)(sA & 63)) {
            const unsigned short* p = xb + (long)e0 * CC + quad * 8;
            cfr[0][0] = *(const bf16x8*)p;
            cfr[0][1] = *(const bf16x8*)(p + 32);
        }
        if (ja < (int)(sB & 63)) {
            const unsigned short* p = xb + (long)e1 * CC + quad * 8;
            cfr[1][0] = *(const bf16x8*)p;
            cfr[1][1] = *(const bf16x8*)(p + 32);
        }
    }
    {
        f1[0][0] = z; f1[0][1] = z; f1[1][0] = z; f1[1][1] = z;
        int e0 = esh[1][row0], e1 = esh[1][row1];
        unsigned sA = seginfo[kb * MT + row0];
        unsigned sB = seginfo[kb * MT + row1];
        if (jb < (int)(sA & 63)) {
            const unsigned short* p = xb + (long)e0 * CC + quad * 8;
            f1[0][0] = *(const bf16x8*)p;
            f1[0][1] = *(const bf16x8*)(p + 32);
        }
        if (jb < (int)(sB & 63)) {
            const unsigned short* p = xb + (long)e1 * CC + quad * 8;
            f1[1][0] = *(const bf16x8*)p;
            f1[1][1] = *(const bf16x8*)(p + 32);
        }
    }
    lds_barrier();   // protect warm-up esh reads from t=0's esh[0] rewrite

    f32x4 acc[2][4];
#pragma unroll
    for (int mt = 0; mt < 2; ++mt)
#pragma unroll
        for (int nt = 0; nt < 4; ++nt) acc[mt][nt] = (f32x4){0.f, 0.f, 0.f, 0.f};

    bf16x8 bfr[4][2];

    for (int t = 0; t < T; ++t) {
        // step1: loader issues entries load for iter t+3 (cursor d)
        int er = 0;
        if (tid < MT) {
            unsigned sd = seginfo[kd * MT + tid];
            er = entries[min((int)(sd >> 6) + jd, TOT - 1)];
        }
        // step2: issue frag loads for iter t+2 (cursor c) from esh[(t+2)%3]
        bf16x8 f2[2][2];
        {
            f2[0][0] = z; f2[0][1] = z; f2[1][0] = z; f2[1][1] = z;
            int slot = (t + 2) % 3;
            int ne0 = esh[slot][row0], ne1 = esh[slot][row1];
            unsigned sc0 = seginfo[kc * MT + row0];
            unsigned sc1 = seginfo[kc * MT + row1];
            if (jc < (int)(sc0 & 63)) {
                const unsigned short* p = xb + (long)ne0 * CC + quad * 8;
                f2[0][0] = *(const bf16x8*)p;
                f2[0][1] = *(const bf16x8*)(p + 32);
            }
            if (jc < (int)(sc1 & 63)) {
                const unsigned short* p = xb + (long)ne1 * CC + quad * 8;
                f2[1][0] = *(const bf16x8*)p;
                f2[1][1] = *(const bf16x8*)(p + 32);
            }
        }
        // step3: B management (block-uniform branch, once per k)
        if (ja == 0) {
#pragma unroll
            for (int nt = 0; nt < 4; ++nt)
#pragma unroll
                for (int kt = 0; kt < 2; ++kt)
                    bfr[nt][kt] = *(const bf16x8*)&Bsh[ka & 1][(nt * 16 + l16) * APAD +
                                                              kt * 32 + quad * 8];
            *(u32x4*)&Bsh[(ka + 1) & 1][brow * APAD + bcol]     = bw0;
            *(u32x4*)&Bsh[(ka + 1) & 1][brow * APAD + bcol + 8] = bw1;
            int kn = ka + 2 < KK ? ka + 2 : KK - 1;
            bw0 = ((const u32x4*)(Wt + kn * CC * CC))[tid * 2];
            bw1 = ((const u32x4*)(Wt + kn * CC * CC))[tid * 2 + 1];
        }
        // step4: MFMA for iter t (16 MFMAs)
#pragma unroll
        for (int mt = 0; mt < 2; ++mt)
#pragma unroll
            for (int nt = 0; nt < 4; ++nt) {
                acc[mt][nt] = __builtin_amdgcn_mfma_f32_16x16x32_bf16(
                    cfr[mt][0], bfr[nt][0], acc[mt][nt], 0, 0, 0);
                acc[mt][nt] = __builtin_amdgcn_mfma_f32_16x16x32_bf16(
                    cfr[mt][1], bfr[nt][1], acc[mt][nt], 0, 0, 0);
            }
        // step5: loader commits entry for iter t+3 into slot (t+3)%3 == t%3
        if (tid < MT) esh[t % 3][tid] = er;
        // step6: rotate frags + advance cursors
        cfr[0][0] = f1[0][0]; cfr[0][1] = f1[0][1];
        cfr[1][0] = f1[1][0]; cfr[1][1] = f1[1][1];
        f1[0][0] = f2[0][0]; f1[0][1] = f2[0][1];
        f1[1][0] = f2[1][0]; f1[1][1] = f2[1][1];
        ka = kb; ja = jb;
        kb = kc; jb = jc;
        kc = kd; jc = jd;
        jd++; if (jd >= maxcnt[kd]) { jd = 0; if (kd < KK - 1) kd++; }
        lds_barrier();
    }

    // epilogue: D row = quad*4 + rr, col = l16 (within each 16x16 tile)
#pragma unroll
    for (int mt = 0; mt < 2; ++mt) {
        int rbase_ = i0 + wave * 32 + mt * 16 + quad * 4;
#pragma unroll
        for (int nt = 0; nt < 4; ++nt) {
            int col = nt * 16 + l16;
#pragma unroll
            for (int rr = 0; rr < 4; ++rr) {
                int gr = rbase_ + rr;
                if (gr < NPTS) y[(long)gr * CC + col] = acc[mt][nt][rr];
            }
        }
    }
}

// ---------------- BN ----------------
__global__ void k_bn_stats(const float* __restrict__ y, float* __restrict__ sums) {
    __shared__ float s1[256], s2[256];
    int t = threadIdx.x;
    int c = t & 63, g = t >> 6;
    float a = 0.f, b = 0.f;
    for (int i = blockIdx.x * 4 + g; i < NPTS; i += gridDim.x * 4) {
        float v = y[(long)i * CC + c];
        a += v; b += v * v;
    }
    s1[t] = a; s2[t] = b;
    __syncthreads();
    if (t < 64) {
        a = s1[t] + s1[t + 64] + s1[t + 128] + s1[t + 192];
        b = s2[t] + s2[t + 64] + s2[t + 128] + s2[t + 192];
        atomicAdd(&sums[t], a);
        atomicAdd(&sums[t + 64], b);
    }
}

__global__ void k_bn_fin(const float* __restrict__ sums, const float* __restrict__ gamma,
                         const float* __restrict__ beta, float* __restrict__ sb) {
    int c = threadIdx.x;   // 64 threads
    float mu  = sums[c] * (1.0f / NPTS);
    float var = sums[c + 64] * (1.0f / NPTS) - mu * mu;
    float s = gamma[c] * rsqrtf(var + EPSBN);
    sb[c] = s;
    sb[c + 64] = beta[c] - mu * s;
}

// a1 = bf16(relu(y*s + b))
__global__ void k_apply(const float* __restrict__ y, const float* __restrict__ sb,
                        unsigned short* __restrict__ ab) {
    int id = blockIdx.x * 256 + threadIdx.x;
    f32x4 v = ((const f32x4*)y)[id];
    int c0 = (id * 4) & 63;
    u16x4 o;
#pragma unroll
    for (int j = 0; j < 4; ++j) {
        float t = fmaxf(v[j] * sb[c0 + j] + sb[64 + c0 + j], 0.f);
        o[j] = f2bf(t);
    }
    ((u16x4*)ab)[id] = o;
}

// out = relu(y*s + b + x)
__global__ void k_final(const float* __restrict__ y, const float* __restrict__ x,
                        const float* __restrict__ sb, float* __restrict__ out) {
    int id = blockIdx.x * 256 + threadIdx.x;
    f32x4 v  = ((const f32x4*)y)[id];
    f32x4 xv = ((const f32x4*)x)[id];
    int c0 = (id * 4) & 63;
    f32x4 o;
#pragma unroll
    for (int j = 0; j < 4; ++j)
        o[j] = fmaxf(v[j] * sb[c0 + j] + sb[64 + c0 + j] + xv[j], 0.f);
    ((f32x4*)out)[id] = o;
}

extern "C" void kernel_launch(void* const* d_in, const int* in_sizes, int n_in,
                              void* d_out, int out_size, void* d_ws, size_t ws_size,
                              hipStream_t stream) {
    const float* x      = (const float*)d_in[0];
    // d_in[1] = norm_points (unused by the reference math)
    const float* W1     = (const float*)d_in[2];
    const float* gamma1 = (const float*)d_in[3];
    const float* beta1  = (const float*)d_in[4];
    const float* W2     = (const float*)d_in[5];
    const float* gamma2 = (const float*)d_in[6];
    const float* beta2  = (const float*)d_in[7];
    const int* in_idx   = (const int*)d_in[8];
    const int* out_idx  = (const int*)d_in[9];
    float* out = (float*)d_out;

    char* w = (char*)d_ws;
    size_t off = 0;
    auto alloc = [&](size_t bytes) -> char* {
        off = (off + 255) & ~(size_t)255;
        char* p = w + off;
        off += bytes;
        return p;
    };
    int*   rcnt    = (int*)  alloc((size_t)KK * NRANGE * 4);
    float* sums    = (float*)alloc(256 * 4);            // [0:128) layer1, [128:256) layer2
    int*   rbase   = (int*)  alloc((size_t)KK * NRANGE * 4);
    float* sb      = (float*)alloc(256 * 4);
    int*   offs    = (int*)  alloc(((size_t)SEGS + 1) * 4);
    int*   entries = (int*)  alloc((size_t)SEGS * 4);
    unsigned short* xbf = (unsigned short*)alloc((size_t)NPTS * CC * 2);
    unsigned short* Wt1 = (unsigned short*)alloc((size_t)KK * CC * CC * 2);
    unsigned short* Wt2 = (unsigned short*)alloc((size_t)KK * CC * CC * 2);
    float* y = (float*)alloc((size_t)NPTS * CC * 4);

    // zero rcnt + sums (contiguous; covers alignment gap)
    size_t zlen = (size_t)((char*)(sums + 256) - (char*)rcnt);
    hipMemsetAsync(rcnt, 0, zlen, stream);

    k_convert_x<<<NPTS * CC / 1024, 256, 0, stream>>>(x, xbf);
    k_prep_w<<<(2 * KK * CC * CC) / 256, 256, 0, stream>>>(W1, W2, Wt1, Wt2);
    k_rhist<<<TOT / CHUNK, 256, 0, stream>>>(out_idx, rcnt);
    k_rscan<<<1, 64, 0, stream>>>(rcnt, rbase, offs);
    k_sort<<<KK * NRANGE, 256, 0, stream>>>(out_idx, in_idx, rbase, offs, entries);

    const int CONVB = (NPTS + MT - 1) / MT;
    k_conv<<<CONVB, 256, 0, stream>>>(xbf, Wt1, offs, entries, y);
    k_bn_stats<<<256, 256, 0, stream>>>(y, sums);
    k_bn_fin<<<1, 64, 0, stream>>>(sums, gamma1, beta1, sb);
    k_apply<<<NPTS * CC / 1024, 256, 0, stream>>>(y, sb, xbf);   // a1 overwrites xbf
    k_conv<<<CONVB, 256, 0, stream>>>(xbf, Wt2, offs, entries, y);
    k_bn_stats<<<256, 256, 0, stream>>>(y, sums + 128);
    k_bn_fin<<<1, 64, 0, stream>>>(sums + 128, gamma2, beta2, sb + 128);
    k_final<<<NPTS * CC / 1024, 256, 0, stream>>>(y, x, sb + 128, out);
}

// Round 9
// 516.100 us; speedup vs baseline: 2.9116x; 1.3040x over previous
//
#include <hip/hip_runtime.h>

#define NPTS 100000
#define CC   64
#define KK   27
#define TOT  (KK * NPTS)        // 2,700,000 edges
#define SEGS (NPTS * KK)        // 2,700,000 (k,dst) segments, k-major
#define EPSBN 1e-5f
#define MT   128                // output rows per conv block
#define APAD 72                 // padded LDS row stride in bf16 elems (144B)

#define NRANGE 32               // dst ranges per slice
#define RSIZE  (NPTS / NRANGE)  // 3125 dsts per range
#define CAP    4608             // LDS bucket capacity (mean 3125 + 26 sigma)
#define CHUNK  12500            // edges per partition block (divides NPTS)
#define NCHK   (NPTS / CHUNK)   // 8 chunks per k-slice
#define NCH    (TOT / CHUNK)    // 216 chunks total

typedef float          f32x4  __attribute__((ext_vector_type(4)));
typedef short          bf16x8 __attribute__((ext_vector_type(8)));
typedef unsigned int   u32x4  __attribute__((ext_vector_type(4)));
typedef unsigned short u16x4  __attribute__((ext_vector_type(4)));
typedef int            i32x4  __attribute__((ext_vector_type(4)));

__device__ __forceinline__ unsigned short f2bf(float f) {
    unsigned int u = __float_as_uint(f);
    u = (u + 0x7fffu + ((u >> 16) & 1u)) >> 16;
    return (unsigned short)u;
}

// barrier that drains LDS only (lgkmcnt(0)) — keeps global prefetches in flight.
__device__ __forceinline__ void lds_barrier() {
    asm volatile("" ::: "memory");
    __builtin_amdgcn_s_waitcnt(0xC07F);
    __builtin_amdgcn_s_barrier();
    asm volatile("" ::: "memory");
}

// ---------------- prep: x -> bf16 ----------------
__global__ void k_convert_x(const float* __restrict__ x, unsigned short* __restrict__ xb) {
    int id = blockIdx.x * 256 + threadIdx.x;
    f32x4 v = ((const f32x4*)x)[id];
    u16x4 o;
#pragma unroll
    for (int j = 0; j < 4; ++j) o[j] = f2bf(v[j]);
    ((u16x4*)xb)[id] = o;
}

// ---------------- prep: W[k][cin][cout] fp32 -> Wt[k][cout][cin] bf16 ----------------
__global__ void k_prep_w(const float* __restrict__ W1, const float* __restrict__ W2,
                         unsigned short* __restrict__ Wt1, unsigned short* __restrict__ Wt2) {
    int id = blockIdx.x * 256 + threadIdx.x;
    int which = id / (KK * CC * CC);
    int r = id % (KK * CC * CC);
    int k = r / (CC * CC);
    int rem = r % (CC * CC);
    int cin = rem / CC, cout = rem % CC;
    const float* W = which ? W2 : W1;
    unsigned short* Wt = which ? Wt2 : Wt1;
    Wt[k * CC * CC + cout * CC + cin] = f2bf(W[r]);
}

// ---------------- CSR build v3: single-read radix partition + tiny sort ----------------
// Phase 1: per-chunk range histogram (also aggregated per (k,range)).
__global__ void k_rhist(const int* __restrict__ out_idx, int* __restrict__ rcnt,
                        int* __restrict__ ccnt) {
    __shared__ int rc[NRANGE];
    int t = threadIdx.x;
    if (t < NRANGE) rc[t] = 0;
    __syncthreads();
    int j0 = blockIdx.x * CHUNK;               // slice-aligned chunk
    int k = j0 / NPTS;
    const i32x4* src = (const i32x4*)(out_idx + j0);
    for (int ii = t; ii < CHUNK / 4; ii += 256) {
        i32x4 d = src[ii];
#pragma unroll
        for (int q = 0; q < 4; ++q) atomicAdd(&rc[d[q] / RSIZE], 1);
    }
    __syncthreads();
    if (t < NRANGE) {
        ccnt[blockIdx.x * NRANGE + t] = rc[t];
        atomicAdd(&rcnt[k * NRANGE + t], rc[t]);
    }
}

// Phase 2: one small block derives bucket bases (rbase) + per-chunk cursors (cbase).
__global__ void k_rscan(const int* __restrict__ rcnt, const int* __restrict__ ccnt,
                        int* __restrict__ rbase, int* __restrict__ cbase,
                        int* __restrict__ offs) {
    int tid = threadIdx.x;                     // <<<1, 896>>>
    if (tid < KK * NRANGE) {
        int k = tid / NRANGE, r = tid % NRANGE;
        int base = k * NPTS;
        for (int rr = 0; rr < r; ++rr) base += rcnt[k * NRANGE + rr];
        rbase[tid] = base;
        int run = base;
        for (int c = 0; c < NCHK; ++c) {
            int ci = (k * NCHK + c) * NRANGE + r;
            cbase[ci] = run;
            run += ccnt[ci];
        }
    }
    if (tid == 0) offs[SEGS] = TOT;
}

// Phase 3: partition each chunk's edges into range buckets (packed (dloc<<17)|src).
__global__ __launch_bounds__(256) void k_part(
    const int* __restrict__ out_idx, const int* __restrict__ in_idx,
    const int* __restrict__ cbase, unsigned* __restrict__ bucket) {
    __shared__ int lcur[NRANGE];
    int t = threadIdx.x;
    if (t < NRANGE) lcur[t] = cbase[blockIdx.x * NRANGE + t];
    __syncthreads();
    int j0 = blockIdx.x * CHUNK;
    const i32x4* dsrc = (const i32x4*)(out_idx + j0);
    const i32x4* ssrc = (const i32x4*)(in_idx + j0);
    for (int ii = t; ii < CHUNK / 4; ii += 256) {
        i32x4 d4 = dsrc[ii];
        i32x4 s4 = ssrc[ii];
#pragma unroll
        for (int q = 0; q < 4; ++q) {
            int d = d4[q];
            int r = d / RSIZE;
            int dloc = d - r * RSIZE;
            int pos = atomicAdd(&lcur[r], 1);
            bucket[pos] = ((unsigned)dloc << 17) | (unsigned)s4[q];
        }
    }
}

// Phase 4: one block per (k,range): counting-sort its ~12.5 KB bucket in LDS.
__global__ __launch_bounds__(256) void k_sort(
    const unsigned* __restrict__ bucket, const int* __restrict__ rbase,
    int* __restrict__ offs, int* __restrict__ entries) {
    __shared__ int cnt[RSIZE];            // 12.5 KB
    __shared__ unsigned list[CAP];        // 18 KB
    __shared__ int psum[256];

    const int t = threadIdx.x;
    const int k = blockIdx.x / NRANGE;
    const int r = blockIdx.x % NRANGE;
    const int dlo = r * RSIZE;
    const int start = rbase[blockIdx.x];
    const int end = (blockIdx.x + 1 < KK * NRANGE) ? rbase[blockIdx.x + 1] : TOT;
    const int n = end - start;

    for (int i = t; i < RSIZE; i += 256) cnt[i] = 0;
    __syncthreads();

    for (int i = t; i < n; i += 256) {
        unsigned u = bucket[start + i];
        if (i < CAP) list[i] = u;
        atomicAdd(&cnt[u >> 17], 1);
    }
    __syncthreads();

    const int TS = (RSIZE + 255) / 256;   // 13
    int vals[TS];
    int s = 0;
#pragma unroll
    for (int q = 0; q < TS; ++q) {
        int i = t * TS + q;
        int v = (i < RSIZE) ? cnt[i] : 0;
        vals[q] = v;
        s += v;
    }
    psum[t] = s;
    __syncthreads();
    for (int o = 1; o < 256; o <<= 1) {
        int pv = (t >= o) ? psum[t - o] : 0;
        __syncthreads();
        psum[t] += pv;
        __syncthreads();
    }
    int run = start + (t ? psum[t - 1] : 0);
#pragma unroll
    for (int q = 0; q < TS; ++q) {
        int i = t * TS + q;
        if (i < RSIZE) {
            offs[k * NPTS + dlo + i] = run;
            cnt[i] = run;
            run += vals[q];
        }
    }
    __syncthreads();

    int nl = n < CAP ? n : CAP;
    for (int i = t; i < nl; i += 256) {
        unsigned u = list[i];
        int p = atomicAdd(&cnt[u >> 17], 1);
        entries[p] = (int)(u & 0x1FFFF);
    }
}

// ---------------- conv: R4-verbatim (rounds + esh ring-2 + LDS B dbuf) ----------------
__global__ __launch_bounds__(256, 3) void k_conv(
    const unsigned short* __restrict__ xb,    // [N][64] bf16
    const unsigned short* __restrict__ Wt,    // [27][cout=64][cin=64] bf16
    const int* __restrict__ offs,             // [SEGS+1], k-major
    const int* __restrict__ entries,          // [TOT] src indices
    float* __restrict__ y)                    // [N][64] fp32
{
    __shared__ __align__(16) unsigned short Bsh[2][CC * APAD];  // 18432 B
    __shared__ unsigned seginfo[KK * MT];                       // 13824 B: (gstart<<6)|cnt
    __shared__ int esh[2][MT];                                  // 1024 B: entry ring
    __shared__ int maxcnt[KK];

    const int tid  = threadIdx.x;
    const int lane = tid & 63;
    const int wave = tid >> 6;
    const int quad = lane >> 4;
    const int l16  = lane & 15;
    const int i0   = blockIdx.x * MT;

    if (tid < KK) maxcnt[tid] = 1;
    __syncthreads();
    for (int idx = tid; idx < KK * MT; idx += 256) {
        int k = idx >> 7;
        int r = idx & (MT - 1);
        int gi = i0 + r;
        unsigned pack = 0;
        int c = 0;
        if (gi < NPTS) {
            int seg = k * NPTS + gi;
            int b = offs[seg];
            c = offs[seg + 1] - b;
            c = c > 63 ? 63 : c;
            pack = ((unsigned)b << 6) | (unsigned)c;
        }
        seginfo[idx] = pack;
        atomicMax(&maxcnt[k], c);
    }
    const int bofs = tid * 16;
    const int brow = bofs >> 6, bcol = bofs & 63;
    u32x4 bw0 = ((const u32x4*)Wt)[tid * 2];
    u32x4 bw1 = ((const u32x4*)Wt)[tid * 2 + 1];
    *(u32x4*)&Bsh[0][brow * APAD + bcol]     = bw0;
    *(u32x4*)&Bsh[0][brow * APAD + bcol + 8] = bw1;
    bw0 = ((const u32x4*)(Wt + CC * CC))[tid * 2];
    bw1 = ((const u32x4*)(Wt + CC * CC))[tid * 2 + 1];
    __syncthreads();

    int T = 0;
    for (int k = 0; k < KK; ++k) T += maxcnt[k];
    int ka = 0, ja = 0;
    int kb = 0, jb = 0;
    int kc = 0, jc = 0;
    {
        jb++; if (jb >= maxcnt[kb]) { jb = 0; if (kb < KK - 1) kb++; }
        kc = kb; jc = jb;
        jc++; if (jc >= maxcnt[kc]) { jc = 0; if (kc < KK - 1) kc++; }
    }

    if (tid < MT) {
        unsigned s0 = seginfo[ka * MT + tid];
        unsigned s1 = seginfo[kb * MT + tid];
        int a0 = min((int)(s0 >> 6) + ja, TOT - 1);
        int a1 = min((int)(s1 >> 6) + jb, TOT - 1);
        esh[0][tid] = entries[a0];
        esh[1][tid] = entries[a1];
    }
    __syncthreads();

    const int row0 = wave * 32 + l16;
    const int row1 = row0 + 16;
    const bf16x8 z = {0, 0, 0, 0, 0, 0, 0, 0};
    bf16x8 cfr[2][2];
    {
        cfr[0][0] = z; cfr[0][1] = z; cfr[1][0] = z; cfr[1][1] = z;
        int e0 = esh[0][row0], e1 = esh[0][row1];
        unsigned sA = seginfo[ka * MT + row0];
        unsigned sB = seginfo[ka * MT + row1];
        if (ja < (int)(sA & 63)) {
            const unsigned short* p = xb + (long)e0 * CC + quad * 8;
            cfr[0][0] = *(const bf16x8*)p;
            cfr[0][1] = *(const bf16x8*)(p + 32);
        }
        if (ja < (int)(sB & 63)) {
            const unsigned short* p = xb + (long)e1 * CC + quad * 8;
            cfr[1][0] = *(const bf16x8*)p;
            cfr[1][1] = *(const bf16x8*)(p + 32);
        }
    }
    lds_barrier();

    f32x4 acc[2][4];
#pragma unroll
    for (int mt = 0; mt < 2; ++mt)
#pragma unroll
        for (int nt = 0; nt < 4; ++nt) acc[mt][nt] = (f32x4){0.f, 0.f, 0.f, 0.f};

    bf16x8 bfr[4][2];

    for (int t = 0; t < T; ++t) {
        int er = 0;
        if (tid < MT) {
            unsigned sc = seginfo[kc * MT + tid];
            int ac = min((int)(sc >> 6) + jc, TOT - 1);
            er = entries[ac];
        }
        bf16x8 nfr[2][2];
        {
            nfr[0][0] = z; nfr[0][1] = z; nfr[1][0] = z; nfr[1][1] = z;
            int slot = (t + 1) & 1;
            int ne0 = esh[slot][row0], ne1 = esh[slot][row1];
            unsigned sb0 = seginfo[kb * MT + row0];
            unsigned sb1 = seginfo[kb * MT + row1];
            if (jb < (int)(sb0 & 63)) {
                const unsigned short* p = xb + (long)ne0 * CC + quad * 8;
                nfr[0][0] = *(const bf16x8*)p;
                nfr[0][1] = *(const bf16x8*)(p + 32);
            }
            if (jb < (int)(sb1 & 63)) {
                const unsigned short* p = xb + (long)ne1 * CC + quad * 8;
                nfr[1][0] = *(const bf16x8*)p;
                nfr[1][1] = *(const bf16x8*)(p + 32);
            }
        }
        if (ja == 0) {
#pragma unroll
            for (int nt = 0; nt < 4; ++nt)
#pragma unroll
                for (int kt = 0; kt < 2; ++kt)
                    bfr[nt][kt] = *(const bf16x8*)&Bsh[ka & 1][(nt * 16 + l16) * APAD +
                                                              kt * 32 + quad * 8];
            *(u32x4*)&Bsh[(ka + 1) & 1][brow * APAD + bcol]     = bw0;
            *(u32x4*)&Bsh[(ka + 1) & 1][brow * APAD + bcol + 8] = bw1;
            int kn = ka + 2 < KK ? ka + 2 : KK - 1;
            bw0 = ((const u32x4*)(Wt + kn * CC * CC))[tid * 2];
            bw1 = ((const u32x4*)(Wt + kn * CC * CC))[tid * 2 + 1];
        }
#pragma unroll
        for (int mt = 0; mt < 2; ++mt)
#pragma unroll
            for (int nt = 0; nt < 4; ++nt) {
                acc[mt][nt] = __builtin_amdgcn_mfma_f32_16x16x32_bf16(
                    cfr[mt][0], bfr[nt][0], acc[mt][nt], 0, 0, 0);
                acc[mt][nt] = __builtin_amdgcn_mfma_f32_16x16x32_bf16(
                    cfr[mt][1], bfr[nt][1], acc[mt][nt], 0, 0, 0);
            }
        if (tid < MT) esh[t & 1][tid] = er;
        cfr[0][0] = nfr[0][0]; cfr[0][1] = nfr[0][1];
        cfr[1][0] = nfr[1][0]; cfr[1][1] = nfr[1][1];
        ka = kb; ja = jb;
        kb = kc; jb = jc;
        jc++; if (jc >= maxcnt[kc]) { jc = 0; if (kc < KK - 1) kc++; }
        lds_barrier();
    }

#pragma unroll
    for (int mt = 0; mt < 2; ++mt) {
        int rbase_ = i0 + wave * 32 + mt * 16 + quad * 4;
#pragma unroll
        for (int nt = 0; nt < 4; ++nt) {
            int col = nt * 16 + l16;
#pragma unroll
            for (int rr = 0; rr < 4; ++rr) {
                int gr = rbase_ + rr;
                if (gr < NPTS) y[(long)gr * CC + col] = acc[mt][nt][rr];
            }
        }
    }
}

// ---------------- BN ----------------
__global__ void k_bn_stats(const float* __restrict__ y, float* __restrict__ sums) {
    __shared__ float s1[256], s2[256];
    int t = threadIdx.x;
    int c = t & 63, g = t >> 6;
    float a = 0.f, b = 0.f;
    for (int i = blockIdx.x * 4 + g; i < NPTS; i += gridDim.x * 4) {
        float v = y[(long)i * CC + c];
        a += v; b += v * v;
    }
    s1[t] = a; s2[t] = b;
    __syncthreads();
    if (t < 64) {
        a = s1[t] + s1[t + 64] + s1[t + 128] + s1[t + 192];
        b = s2[t] + s2[t + 64] + s2[t + 128] + s2[t + 192];
        atomicAdd(&sums[t], a);
        atomicAdd(&sums[t + 64], b);
    }
}

__global__ void k_bn_fin(const float* __restrict__ sums, const float* __restrict__ gamma,
                         const float* __restrict__ beta, float* __restrict__ sb) {
    int c = threadIdx.x;   // 64 threads
    float mu  = sums[c] * (1.0f / NPTS);
    float var = sums[c + 64] * (1.0f / NPTS) - mu * mu;
    float s = gamma[c] * rsqrtf(var + EPSBN);
    sb[c] = s;
    sb[c + 64] = beta[c] - mu * s;
}

// a1 = bf16(relu(y*s + b))
__global__ void k_apply(const float* __restrict__ y, const float* __restrict__ sb,
                        unsigned short* __restrict__ ab) {
    int id = blockIdx.x * 256 + threadIdx.x;
    f32x4 v = ((const f32x4*)y)[id];
    int c0 = (id * 4) & 63;
    u16x4 o;
#pragma unroll
    for (int j = 0; j < 4; ++j) {
        float t = fmaxf(v[j] * sb[c0 + j] + sb[64 + c0 + j], 0.f);
        o[j] = f2bf(t);
    }
    ((u16x4*)ab)[id] = o;
}

// out = relu(y*s + b + x)
__global__ void k_final(const float* __restrict__ y, const float* __restrict__ x,
                        const float* __restrict__ sb, float* __restrict__ out) {
    int id = blockIdx.x * 256 + threadIdx.x;
    f32x4 v  = ((const f32x4*)y)[id];
    f32x4 xv = ((const f32x4*)x)[id];
    int c0 = (id * 4) & 63;
    f32x4 o;
#pragma unroll
    for (int j = 0; j < 4; ++j)
        o[j] = fmaxf(v[j] * sb[c0 + j] + sb[64 + c0 + j] + xv[j], 0.f);
    ((f32x4*)out)[id] = o;
}

extern "C" void kernel_launch(void* const* d_in, const int* in_sizes, int n_in,
                              void* d_out, int out_size, void* d_ws, size_t ws_size,
                              hipStream_t stream) {
    const float* x      = (const float*)d_in[0];
    // d_in[1] = norm_points (unused by the reference math)
    const float* W1     = (const float*)d_in[2];
    const float* gamma1 = (const float*)d_in[3];
    const float* beta1  = (const float*)d_in[4];
    const float* W2     = (const float*)d_in[5];
    const float* gamma2 = (const float*)d_in[6];
    const float* beta2  = (const float*)d_in[7];
    const int* in_idx   = (const int*)d_in[8];
    const int* out_idx  = (const int*)d_in[9];
    float* out = (float*)d_out;

    char* w = (char*)d_ws;
    size_t off = 0;
    auto alloc = [&](size_t bytes) -> char* {
        off = (off + 255) & ~(size_t)255;
        char* p = w + off;
        off += bytes;
        return p;
    };
    int*   rcnt    = (int*)  alloc((size_t)KK * NRANGE * 4);
    float* sums    = (float*)alloc(256 * 4);            // [0:128) layer1, [128:256) layer2
    int*   rbase   = (int*)  alloc((size_t)KK * NRANGE * 4);
    float* sb      = (float*)alloc(256 * 4);
    int*   ccnt    = (int*)  alloc((size_t)NCH * NRANGE * 4);
    int*   cbase   = (int*)  alloc((size_t)NCH * NRANGE * 4);
    int*   offs    = (int*)  alloc(((size_t)SEGS + 1) * 4);
    int*   entries = (int*)  alloc((size_t)SEGS * 4);
    unsigned* bucket = (unsigned*)alloc((size_t)SEGS * 4);
    unsigned short* xbf = (unsigned short*)alloc((size_t)NPTS * CC * 2);
    unsigned short* Wt1 = (unsigned short*)alloc((size_t)KK * CC * CC * 2);
    unsigned short* Wt2 = (unsigned short*)alloc((size_t)KK * CC * CC * 2);
    float* y = (float*)alloc((size_t)NPTS * CC * 4);

    // zero rcnt + sums (contiguous; covers alignment gap)
    size_t zlen = (size_t)((char*)(sums + 256) - (char*)rcnt);
    hipMemsetAsync(rcnt, 0, zlen, stream);

    k_convert_x<<<NPTS * CC / 1024, 256, 0, stream>>>(x, xbf);
    k_prep_w<<<(2 * KK * CC * CC) / 256, 256, 0, stream>>>(W1, W2, Wt1, Wt2);
    k_rhist<<<NCH, 256, 0, stream>>>(out_idx, rcnt, ccnt);
    k_rscan<<<1, 896, 0, stream>>>(rcnt, ccnt, rbase, cbase, offs);
    k_part<<<NCH, 256, 0, stream>>>(out_idx, in_idx, cbase, bucket);
    k_sort<<<KK * NRANGE, 256, 0, stream>>>(bucket, rbase, offs, entries);

    const int CONVB = (NPTS + MT - 1) / MT;
    k_conv<<<CONVB, 256, 0, stream>>>(xbf, Wt1, offs, entries, y);
    k_bn_stats<<<256, 256, 0, stream>>>(y, sums);
    k_bn_fin<<<1, 64, 0, stream>>>(sums, gamma1, beta1, sb);
    k_apply<<<NPTS * CC / 1024, 256, 0, stream>>>(y, sb, xbf);   // a1 overwrites xbf
    k_conv<<<CONVB, 256, 0, stream>>>(xbf, Wt2, offs, entries, y);
    k_bn_stats<<<256, 256, 0, stream>>>(y, sums + 128);
    k_bn_fin<<<1, 64, 0, stream>>>(sums + 128, gamma2, beta2, sb + 128);
    k_final<<<NPTS * CC / 1024, 256, 0, stream>>>(y, x, sb + 128, out);
}

// Round 10
// 467.486 us; speedup vs baseline: 3.2144x; 1.1040x over previous
//
#include <hip/hip_runtime.h>

#define NPTS 100000
#define CC   64
#define KK   27
#define TOT  (KK * NPTS)        // 2,700,000 edges
#define SEGS (NPTS * KK)        // 2,700,000 (k,dst) segments, k-major
#define EPSBN 1e-5f
#define MT   128                // output rows per conv block
#define APAD 72                 // padded LDS row stride in bf16 elems (144B)

#define NRANGE 32               // dst ranges per slice
#define RSIZE  (NPTS / NRANGE)  // 3125 dsts per range
#define CAP    4608             // LDS bucket capacity (mean 3125 + 26 sigma)
#define CHUNK  12500            // edges per partition block (divides NPTS)
#define NCHK   (NPTS / CHUNK)   // 8 chunks per k-slice
#define NCH    (TOT / CHUNK)    // 216 chunks total

#define XBLK   (NPTS * CC / 1024)      // 6250 blocks for x conversion
#define WBLK   (2 * KK * CC * CC / 256) // 864 blocks for W prep

typedef float          f32x4  __attribute__((ext_vector_type(4)));
typedef short          bf16x8 __attribute__((ext_vector_type(8)));
typedef unsigned int   u32x4  __attribute__((ext_vector_type(4)));
typedef unsigned short u16x4  __attribute__((ext_vector_type(4)));
typedef int            i32x4  __attribute__((ext_vector_type(4)));

__device__ __forceinline__ unsigned short f2bf(float f) {
    unsigned int u = __float_as_uint(f);
    u = (u + 0x7fffu + ((u >> 16) & 1u)) >> 16;
    return (unsigned short)u;
}

// barrier that drains LDS only (lgkmcnt(0)) — keeps global prefetches in flight.
__device__ __forceinline__ void lds_barrier() {
    asm volatile("" ::: "memory");
    __builtin_amdgcn_s_waitcnt(0xC07F);
    __builtin_amdgcn_s_barrier();
    asm volatile("" ::: "memory");
}

// ---------------- prep: x -> bf16 (blocks [0,XBLK)) + W -> Wt (blocks [XBLK,..)) ----
__global__ void k_prep(const float* __restrict__ x,
                       const float* __restrict__ W1, const float* __restrict__ W2,
                       unsigned short* __restrict__ xb,
                       unsigned short* __restrict__ Wt1, unsigned short* __restrict__ Wt2) {
    int b = blockIdx.x;
    if (b < XBLK) {
        int id = b * 256 + threadIdx.x;
        f32x4 v = ((const f32x4*)x)[id];
        u16x4 o;
#pragma unroll
        for (int j = 0; j < 4; ++j) o[j] = f2bf(v[j]);
        ((u16x4*)xb)[id] = o;
    } else {
        int id = (b - XBLK) * 256 + threadIdx.x;
        int which = id / (KK * CC * CC);
        int r = id % (KK * CC * CC);
        int k = r / (CC * CC);
        int rem = r % (CC * CC);
        int cin = rem / CC, cout = rem % CC;
        const float* W = which ? W2 : W1;
        unsigned short* Wt = which ? Wt2 : Wt1;
        Wt[k * CC * CC + cout * CC + cin] = f2bf(W[r]);
    }
}

// ---------------- CSR build: single-read radix partition + tiny sort ----------------
__global__ void k_rhist(const int* __restrict__ out_idx, int* __restrict__ rcnt,
                        int* __restrict__ ccnt) {
    __shared__ int rc[NRANGE];
    int t = threadIdx.x;
    if (t < NRANGE) rc[t] = 0;
    __syncthreads();
    int j0 = blockIdx.x * CHUNK;               // slice-aligned chunk
    int k = j0 / NPTS;
    const i32x4* src = (const i32x4*)(out_idx + j0);
    for (int ii = t; ii < CHUNK / 4; ii += 256) {
        i32x4 d = src[ii];
#pragma unroll
        for (int q = 0; q < 4; ++q) atomicAdd(&rc[d[q] / RSIZE], 1);
    }
    __syncthreads();
    if (t < NRANGE) {
        ccnt[blockIdx.x * NRANGE + t] = rc[t];
        atomicAdd(&rcnt[k * NRANGE + t], rc[t]);
    }
}

__global__ void k_rscan(const int* __restrict__ rcnt, const int* __restrict__ ccnt,
                        int* __restrict__ rbase, int* __restrict__ cbase,
                        int* __restrict__ offs) {
    int tid = threadIdx.x;                     // <<<1, 896>>>
    if (tid < KK * NRANGE) {
        int k = tid / NRANGE, r = tid % NRANGE;
        int base = k * NPTS;
        for (int rr = 0; rr < r; ++rr) base += rcnt[k * NRANGE + rr];
        rbase[tid] = base;
        int run = base;
        for (int c = 0; c < NCHK; ++c) {
            int ci = (k * NCHK + c) * NRANGE + r;
            cbase[ci] = run;
            run += ccnt[ci];
        }
    }
    if (tid == 0) offs[SEGS] = TOT;
}

__global__ __launch_bounds__(256) void k_part(
    const int* __restrict__ out_idx, const int* __restrict__ in_idx,
    const int* __restrict__ cbase, unsigned* __restrict__ bucket) {
    __shared__ int lcur[NRANGE];
    int t = threadIdx.x;
    if (t < NRANGE) lcur[t] = cbase[blockIdx.x * NRANGE + t];
    __syncthreads();
    int j0 = blockIdx.x * CHUNK;
    const i32x4* dsrc = (const i32x4*)(out_idx + j0);
    const i32x4* ssrc = (const i32x4*)(in_idx + j0);
    for (int ii = t; ii < CHUNK / 4; ii += 256) {
        i32x4 d4 = dsrc[ii];
        i32x4 s4 = ssrc[ii];
#pragma unroll
        for (int q = 0; q < 4; ++q) {
            int d = d4[q];
            int r = d / RSIZE;
            int dloc = d - r * RSIZE;
            int pos = atomicAdd(&lcur[r], 1);
            bucket[pos] = ((unsigned)dloc << 17) | (unsigned)s4[q];
        }
    }
}

__global__ __launch_bounds__(256) void k_sort(
    const unsigned* __restrict__ bucket, const int* __restrict__ rbase,
    int* __restrict__ offs, int* __restrict__ entries) {
    __shared__ int cnt[RSIZE];            // 12.5 KB
    __shared__ unsigned list[CAP];        // 18 KB
    __shared__ int psum[256];

    const int t = threadIdx.x;
    const int k = blockIdx.x / NRANGE;
    const int r = blockIdx.x % NRANGE;
    const int dlo = r * RSIZE;
    const int start = rbase[blockIdx.x];
    const int end = (blockIdx.x + 1 < KK * NRANGE) ? rbase[blockIdx.x + 1] : TOT;
    const int n = end - start;

    for (int i = t; i < RSIZE; i += 256) cnt[i] = 0;
    __syncthreads();

    for (int i = t; i < n; i += 256) {
        unsigned u = bucket[start + i];
        if (i < CAP) list[i] = u;
        atomicAdd(&cnt[u >> 17], 1);
    }
    __syncthreads();

    const int TS = (RSIZE + 255) / 256;   // 13
    int vals[TS];
    int s = 0;
#pragma unroll
    for (int q = 0; q < TS; ++q) {
        int i = t * TS + q;
        int v = (i < RSIZE) ? cnt[i] : 0;
        vals[q] = v;
        s += v;
    }
    psum[t] = s;
    __syncthreads();
    for (int o = 1; o < 256; o <<= 1) {
        int pv = (t >= o) ? psum[t - o] : 0;
        __syncthreads();
        psum[t] += pv;
        __syncthreads();
    }
    int run = start + (t ? psum[t - 1] : 0);
#pragma unroll
    for (int q = 0; q < TS; ++q) {
        int i = t * TS + q;
        if (i < RSIZE) {
            offs[k * NPTS + dlo + i] = run;
            cnt[i] = run;
            run += vals[q];
        }
    }
    __syncthreads();

    int nl = n < CAP ? n : CAP;
    for (int i = t; i < nl; i += 256) {
        unsigned u = list[i];
        int p = atomicAdd(&cnt[u >> 17], 1);
        entries[p] = (int)(u & 0x1FFFF);
    }
}

// ---------------- conv: R4 hot loop + fused BN-stats epilogue ----------------
__global__ __launch_bounds__(256, 3) void k_conv(
    const unsigned short* __restrict__ xb,    // [N][64] bf16
    const unsigned short* __restrict__ Wt,    // [27][cout=64][cin=64] bf16
    const int* __restrict__ offs,             // [SEGS+1], k-major
    const int* __restrict__ entries,          // [TOT] src indices
    float* __restrict__ y,                    // [N][64] fp32
    float* __restrict__ sums)                 // [128]: sum, sumsq per channel
{
    __shared__ __align__(16) unsigned short Bsh[2][CC * APAD];  // 18432 B
    __shared__ unsigned seginfo[KK * MT];                       // 13824 B: (gstart<<6)|cnt
    __shared__ int esh[2][MT];                                  // 1024 B: entry ring
    __shared__ int maxcnt[KK];

    const int tid  = threadIdx.x;
    const int lane = tid & 63;
    const int wave = tid >> 6;
    const int quad = lane >> 4;
    const int l16  = lane & 15;
    const int i0   = blockIdx.x * MT;

    if (tid < KK) maxcnt[tid] = 1;
    __syncthreads();
    for (int idx = tid; idx < KK * MT; idx += 256) {
        int k = idx >> 7;
        int r = idx & (MT - 1);
        int gi = i0 + r;
        unsigned pack = 0;
        int c = 0;
        if (gi < NPTS) {
            int seg = k * NPTS + gi;
            int b = offs[seg];
            c = offs[seg + 1] - b;
            c = c > 63 ? 63 : c;
            pack = ((unsigned)b << 6) | (unsigned)c;
        }
        seginfo[idx] = pack;
        atomicMax(&maxcnt[k], c);
    }
    const int bofs = tid * 16;
    const int brow = bofs >> 6, bcol = bofs & 63;
    u32x4 bw0 = ((const u32x4*)Wt)[tid * 2];
    u32x4 bw1 = ((const u32x4*)Wt)[tid * 2 + 1];
    *(u32x4*)&Bsh[0][brow * APAD + bcol]     = bw0;
    *(u32x4*)&Bsh[0][brow * APAD + bcol + 8] = bw1;
    bw0 = ((const u32x4*)(Wt + CC * CC))[tid * 2];
    bw1 = ((const u32x4*)(Wt + CC * CC))[tid * 2 + 1];
    __syncthreads();

    int T = 0;
    for (int k = 0; k < KK; ++k) T += maxcnt[k];
    int ka = 0, ja = 0;
    int kb = 0, jb = 0;
    int kc = 0, jc = 0;
    {
        jb++; if (jb >= maxcnt[kb]) { jb = 0; if (kb < KK - 1) kb++; }
        kc = kb; jc = jb;
        jc++; if (jc >= maxcnt[kc]) { jc = 0; if (kc < KK - 1) kc++; }
    }

    if (tid < MT) {
        unsigned s0 = seginfo[ka * MT + tid];
        unsigned s1 = seginfo[kb * MT + tid];
        int a0 = min((int)(s0 >> 6) + ja, TOT - 1);
        int a1 = min((int)(s1 >> 6) + jb, TOT - 1);
        esh[0][tid] = entries[a0];
        esh[1][tid] = entries[a1];
    }
    __syncthreads();

    const int row0 = wave * 32 + l16;
    const int row1 = row0 + 16;
    const bf16x8 z = {0, 0, 0, 0, 0, 0, 0, 0};
    bf16x8 cfr[2][2];
    {
        cfr[0][0] = z; cfr[0][1] = z; cfr[1][0] = z; cfr[1][1] = z;
        int e0 = esh[0][row0], e1 = esh[0][row1];
        unsigned sA = seginfo[ka * MT + row0];
        unsigned sB = seginfo[ka * MT + row1];
        if (ja < (int)(sA & 63)) {
            const unsigned short* p = xb + (long)e0 * CC + quad * 8;
            cfr[0][0] = *(const bf16x8*)p;
            cfr[0][1] = *(const bf16x8*)(p + 32);
        }
        if (ja < (int)(sB & 63)) {
            const unsigned short* p = xb + (long)e1 * CC + quad * 8;
            cfr[1][0] = *(const bf16x8*)p;
            cfr[1][1] = *(const bf16x8*)(p + 32);
        }
    }
    lds_barrier();

    f32x4 acc[2][4];
#pragma unroll
    for (int mt = 0; mt < 2; ++mt)
#pragma unroll
        for (int nt = 0; nt < 4; ++nt) acc[mt][nt] = (f32x4){0.f, 0.f, 0.f, 0.f};

    bf16x8 bfr[4][2];

    for (int t = 0; t < T; ++t) {
        int er = 0;
        if (tid < MT) {
            unsigned sc = seginfo[kc * MT + tid];
            int ac = min((int)(sc >> 6) + jc, TOT - 1);
            er = entries[ac];
        }
        bf16x8 nfr[2][2];
        {
            nfr[0][0] = z; nfr[0][1] = z; nfr[1][0] = z; nfr[1][1] = z;
            int slot = (t + 1) & 1;
            int ne0 = esh[slot][row0], ne1 = esh[slot][row1];
            unsigned sb0 = seginfo[kb * MT + row0];
            unsigned sb1 = seginfo[kb * MT + row1];
            if (jb < (int)(sb0 & 63)) {
                const unsigned short* p = xb + (long)ne0 * CC + quad * 8;
                nfr[0][0] = *(const bf16x8*)p;
                nfr[0][1] = *(const bf16x8*)(p + 32);
            }
            if (jb < (int)(sb1 & 63)) {
                const unsigned short* p = xb + (long)ne1 * CC + quad * 8;
                nfr[1][0] = *(const bf16x8*)p;
                nfr[1][1] = *(const bf16x8*)(p + 32);
            }
        }
        if (ja == 0) {
#pragma unroll
            for (int nt = 0; nt < 4; ++nt)
#pragma unroll
                for (int kt = 0; kt < 2; ++kt)
                    bfr[nt][kt] = *(const bf16x8*)&Bsh[ka & 1][(nt * 16 + l16) * APAD +
                                                              kt * 32 + quad * 8];
            *(u32x4*)&Bsh[(ka + 1) & 1][brow * APAD + bcol]     = bw0;
            *(u32x4*)&Bsh[(ka + 1) & 1][brow * APAD + bcol + 8] = bw1;
            int kn = ka + 2 < KK ? ka + 2 : KK - 1;
            bw0 = ((const u32x4*)(Wt + kn * CC * CC))[tid * 2];
            bw1 = ((const u32x4*)(Wt + kn * CC * CC))[tid * 2 + 1];
        }
#pragma unroll
        for (int mt = 0; mt < 2; ++mt)
#pragma unroll
            for (int nt = 0; nt < 4; ++nt) {
                acc[mt][nt] = __builtin_amdgcn_mfma_f32_16x16x32_bf16(
                    cfr[mt][0], bfr[nt][0], acc[mt][nt], 0, 0, 0);
                acc[mt][nt] = __builtin_amdgcn_mfma_f32_16x16x32_bf16(
                    cfr[mt][1], bfr[nt][1], acc[mt][nt], 0, 0, 0);
            }
        if (tid < MT) esh[t & 1][tid] = er;
        cfr[0][0] = nfr[0][0]; cfr[0][1] = nfr[0][1];
        cfr[1][0] = nfr[1][0]; cfr[1][1] = nfr[1][1];
        ka = kb; ja = jb;
        kb = kc; jb = jc;
        jc++; if (jc >= maxcnt[kc]) { jc = 0; if (kc < KK - 1) kc++; }
        lds_barrier();
    }

    // epilogue: write y + fused BN partial sums (Bsh is dead -> alias as ssum)
    float* ssum = (float*)&Bsh[0][0];
    if (tid < 128) ssum[tid] = 0.f;
    __syncthreads();

    float cs[4], cq[4];
#pragma unroll
    for (int nt = 0; nt < 4; ++nt) { cs[nt] = 0.f; cq[nt] = 0.f; }
#pragma unroll
    for (int mt = 0; mt < 2; ++mt) {
        int rbase_ = i0 + wave * 32 + mt * 16 + quad * 4;
#pragma unroll
        for (int nt = 0; nt < 4; ++nt) {
            int col = nt * 16 + l16;
#pragma unroll
            for (int rr = 0; rr < 4; ++rr) {
                int gr = rbase_ + rr;
                if (gr < NPTS) {
                    float v = acc[mt][nt][rr];
                    y[(long)gr * CC + col] = v;
                    cs[nt] += v;
                    cq[nt] += v * v;
                }
            }
        }
    }
    // lanes {l16, l16+16, l16+32, l16+48} share col -> xor-reduce over 16, 32
#pragma unroll
    for (int nt = 0; nt < 4; ++nt) {
        cs[nt] += __shfl_xor(cs[nt], 16, 64);
        cs[nt] += __shfl_xor(cs[nt], 32, 64);
        cq[nt] += __shfl_xor(cq[nt], 16, 64);
        cq[nt] += __shfl_xor(cq[nt], 32, 64);
    }
    if (quad == 0) {
#pragma unroll
        for (int nt = 0; nt < 4; ++nt) {
            atomicAdd(&ssum[nt * 16 + l16], cs[nt]);
            atomicAdd(&ssum[64 + nt * 16 + l16], cq[nt]);
        }
    }
    __syncthreads();
    if (tid < 128) atomicAdd(&sums[tid], ssum[tid]);
}

// ---------------- a1 = bf16(relu(y*s + b)) with inline BN finalize ----------------
__global__ void k_apply(const float* __restrict__ y, const float* __restrict__ sums,
                        const float* __restrict__ gamma, const float* __restrict__ beta,
                        unsigned short* __restrict__ ab) {
    __shared__ float sb[128];
    int t = threadIdx.x;
    if (t < 64) {
        float mu  = sums[t] * (1.0f / NPTS);
        float var = sums[t + 64] * (1.0f / NPTS) - mu * mu;
        float s = gamma[t] * rsqrtf(var + EPSBN);
        sb[t] = s;
        sb[t + 64] = beta[t] - mu * s;
    }
    __syncthreads();
    int id = blockIdx.x * 256 + t;
    f32x4 v = ((const f32x4*)y)[id];
    int c0 = (id * 4) & 63;
    u16x4 o;
#pragma unroll
    for (int j = 0; j < 4; ++j) {
        float r = fmaxf(v[j] * sb[c0 + j] + sb[64 + c0 + j], 0.f);
        o[j] = f2bf(r);
    }
    ((u16x4*)ab)[id] = o;
}

// ---------------- out = relu(y*s + b + x) with inline BN finalize ----------------
__global__ void k_final(const float* __restrict__ y, const float* __restrict__ x,
                        const float* __restrict__ sums,
                        const float* __restrict__ gamma, const float* __restrict__ beta,
                        float* __restrict__ out) {
    __shared__ float sb[128];
    int t = threadIdx.x;
    if (t < 64) {
        float mu  = sums[t] * (1.0f / NPTS);
        float var = sums[t + 64] * (1.0f / NPTS) - mu * mu;
        float s = gamma[t] * rsqrtf(var + EPSBN);
        sb[t] = s;
        sb[t + 64] = beta[t] - mu * s;
    }
    __syncthreads();
    int id = blockIdx.x * 256 + t;
    f32x4 v  = ((const f32x4*)y)[id];
    f32x4 xv = ((const f32x4*)x)[id];
    int c0 = (id * 4) & 63;
    f32x4 o;
#pragma unroll
    for (int j = 0; j < 4; ++j)
        o[j] = fmaxf(v[j] * sb[c0 + j] + sb[64 + c0 + j] + xv[j], 0.f);
    ((f32x4*)out)[id] = o;
}

extern "C" void kernel_launch(void* const* d_in, const int* in_sizes, int n_in,
                              void* d_out, int out_size, void* d_ws, size_t ws_size,
                              hipStream_t stream) {
    const float* x      = (const float*)d_in[0];
    // d_in[1] = norm_points (unused by the reference math)
    const float* W1     = (const float*)d_in[2];
    const float* gamma1 = (const float*)d_in[3];
    const float* beta1  = (const float*)d_in[4];
    const float* W2     = (const float*)d_in[5];
    const float* gamma2 = (const float*)d_in[6];
    const float* beta2  = (const float*)d_in[7];
    const int* in_idx   = (const int*)d_in[8];
    const int* out_idx  = (const int*)d_in[9];
    float* out = (float*)d_out;

    char* w = (char*)d_ws;
    size_t off = 0;
    auto alloc = [&](size_t bytes) -> char* {
        off = (off + 255) & ~(size_t)255;
        char* p = w + off;
        off += bytes;
        return p;
    };
    int*   rcnt    = (int*)  alloc((size_t)KK * NRANGE * 4);
    float* sums    = (float*)alloc(256 * 4);            // [0:128) layer1, [128:256) layer2
    int*   rbase   = (int*)  alloc((size_t)KK * NRANGE * 4);
    int*   ccnt    = (int*)  alloc((size_t)NCH * NRANGE * 4);
    int*   cbase   = (int*)  alloc((size_t)NCH * NRANGE * 4);
    int*   offs    = (int*)  alloc(((size_t)SEGS + 1) * 4);
    int*   entries = (int*)  alloc((size_t)SEGS * 4);
    unsigned* bucket = (unsigned*)alloc((size_t)SEGS * 4);
    unsigned short* xbf = (unsigned short*)alloc((size_t)NPTS * CC * 2);
    unsigned short* Wt1 = (unsigned short*)alloc((size_t)KK * CC * CC * 2);
    unsigned short* Wt2 = (unsigned short*)alloc((size_t)KK * CC * CC * 2);
    float* y = (float*)alloc((size_t)NPTS * CC * 4);

    // zero rcnt + sums (contiguous; covers alignment gap)
    size_t zlen = (size_t)((char*)(sums + 256) - (char*)rcnt);
    hipMemsetAsync(rcnt, 0, zlen, stream);

    k_prep<<<XBLK + WBLK, 256, 0, stream>>>(x, W1, W2, xbf, Wt1, Wt2);
    k_rhist<<<NCH, 256, 0, stream>>>(out_idx, rcnt, ccnt);
    k_rscan<<<1, 896, 0, stream>>>(rcnt, ccnt, rbase, cbase, offs);
    k_part<<<NCH, 256, 0, stream>>>(out_idx, in_idx, cbase, bucket);
    k_sort<<<KK * NRANGE, 256, 0, stream>>>(bucket, rbase, offs, entries);

    const int CONVB = (NPTS + MT - 1) / MT;
    k_conv<<<CONVB, 256, 0, stream>>>(xbf, Wt1, offs, entries, y, sums);
    k_apply<<<NPTS * CC / 1024, 256, 0, stream>>>(y, sums, gamma1, beta1, xbf);  // a1 -> xbf
    k_conv<<<CONVB, 256, 0, stream>>>(xbf, Wt2, offs, entries, y, sums + 128);
    k_final<<<NPTS * CC / 1024, 256, 0, stream>>>(y, x, sums + 128, gamma2, beta2, out);
}